// Round 9
// baseline (185.331 us; speedup 1.0000x reference)
//
#include <hip/hip_runtime.h>
#include <hip/hip_bf16.h>
#include <math.h>

typedef __attribute__((ext_vector_type(8))) short short8;
typedef __attribute__((ext_vector_type(4))) float f32x4;

#define TT 4096
#define DM 1024
#define NH 16
#define HD 64
#define PSTR 168   // attn LDS row stride in halfwords (84 dwords == 20 mod 32 banks)

typedef __attribute__((address_space(3))) unsigned int lds_u32;
typedef __attribute__((address_space(1))) unsigned int glb_u32;

__device__ __forceinline__ void async_cp16(const void* g, void* l) {
    __builtin_amdgcn_global_load_lds((glb_u32*)g, (lds_u32*)l, 16, 0, 0);
}

// Fused fp32 -> bf16 cast for x + Wq/Wk/Wv/Wo + Wg.
__global__ __launch_bounds__(256) void cast_all(
    const float* __restrict__ x,  const float* __restrict__ wq,
    const float* __restrict__ wk, const float* __restrict__ wv,
    const float* __restrict__ wo, const float* __restrict__ wg,
    __hip_bfloat16* __restrict__ xb,  __hip_bfloat16* __restrict__ wqb,
    __hip_bfloat16* __restrict__ wkb, __hip_bfloat16* __restrict__ wvb,
    __hip_bfloat16* __restrict__ wob, __hip_bfloat16* __restrict__ wgb)
{
    int b = blockIdx.x;
    const float* src;
    __hip_bfloat16* dst;
    size_t base;
    if (b < 4096)      { src = x;  dst = xb;  base = (size_t)b * 1024; }
    else if (b < 5120) { src = wq; dst = wqb; base = (size_t)(b - 4096) * 1024; }
    else if (b < 6144) { src = wk; dst = wkb; base = (size_t)(b - 5120) * 1024; }
    else if (b < 7168) { src = wv; dst = wvb; base = (size_t)(b - 6144) * 1024; }
    else if (b < 8192) { src = wo; dst = wob; base = (size_t)(b - 7168) * 1024; }
    else               { src = wg; dst = wgb; base = (size_t)(b - 8192) * 1024; }
    size_t i = base + (size_t)threadIdx.x * 4;
    float4 v = *(const float4*)(src + i);
    __hip_bfloat16 h0 = (__hip_bfloat16)v.x;
    __hip_bfloat16 h1 = (__hip_bfloat16)v.y;
    __hip_bfloat16 h2 = (__hip_bfloat16)v.z;
    __hip_bfloat16 h3 = (__hip_bfloat16)v.w;
    ushort4 u;
    u.x = *(unsigned short*)&h0;
    u.y = *(unsigned short*)&h1;
    u.z = *(unsigned short*)&h2;
    u.w = *(unsigned short*)&h3;
    *(ushort4*)((unsigned short*)dst + i) = u;
}

// 128x128-tile GEMM, BK=64, single-buffered (32 KB LDS). Halves barrier count
// vs BK=32 with identical DMA/ds_read/MFMA totals. Row = 64 halfwords (128 B);
// chunk swizzle slot^(row&7) applied on the global-address side of the DMA.
// Grid (M/128, 8*ngroups): group = blockIdx.y>>3 selects B/bias/O (QKV fusion).
template <typename OutT>
__global__ __launch_bounds__(256) void gemm128(
    const __hip_bfloat16* __restrict__ A,
    const __hip_bfloat16* __restrict__ B0, const __hip_bfloat16* __restrict__ B1,
    const __hip_bfloat16* __restrict__ B2,
    const float* __restrict__ c0, const float* __restrict__ c1, const float* __restrict__ c2,
    OutT* __restrict__ O0, OutT* __restrict__ O1, OutT* __restrict__ O2)
{
    const int K = DM;
    __shared__ __align__(16) unsigned short sA[128 * 64];
    __shared__ __align__(16) unsigned short sB[128 * 64];

    const int grp = blockIdx.y >> 3;
    const __hip_bfloat16* B = grp == 0 ? B0 : (grp == 1 ? B1 : B2);
    const float* bias       = grp == 0 ? c0 : (grp == 1 ? c1 : c2);
    OutT* O                 = grp == 0 ? O0 : (grp == 1 ? O1 : O2);

    const int tid  = threadIdx.x;
    const int w    = tid >> 6;
    const int lane = tid & 63;
    const int l16  = lane & 15;
    const int quad = lane >> 4;
    const int rowBase = blockIdx.x * 128;
    const int colBase = (blockIdx.y & 7) * 128;

    // staging: per call, 8 rows x 8 slots of 16B; lane = (r8, slot);
    // global chunk = slot ^ r8 (row&7 == r8 for 8-row-aligned calls).
    const int r8   = lane >> 3;
    const int slot = lane & 7;
    const int gchunk = slot ^ r8;
    const __hip_bfloat16* gA = A + (size_t)(rowBase + w * 32 + r8) * K + gchunk * 8;
    const __hip_bfloat16* gB = B + (size_t)(colBase + w * 32 + r8) * K + gchunk * 8;
    unsigned short* lA = sA + w * 32 * 64;
    unsigned short* lB = sB + w * 32 * 64;

    const int fs = l16 & 7;            // fragment-read swizzle (row&7 == l16&7)
    const int mrow = (w & 1) * 64;
    const int ncol = (w >> 1) * 64;

    f32x4 acc[4][4];
#pragma unroll
    for (int i = 0; i < 4; ++i)
#pragma unroll
        for (int j = 0; j < 4; ++j) acc[i][j] = (f32x4){0.f, 0.f, 0.f, 0.f};

    for (int k0 = 0; k0 < K; k0 += 64) {
        __syncthreads();
        async_cp16(gA + k0,                      lA);
        async_cp16(gA + k0 + (size_t) 8 * K,     lA +  8 * 64);
        async_cp16(gA + k0 + (size_t)16 * K,     lA + 16 * 64);
        async_cp16(gA + k0 + (size_t)24 * K,     lA + 24 * 64);
        async_cp16(gB + k0,                      lB);
        async_cp16(gB + k0 + (size_t) 8 * K,     lB +  8 * 64);
        async_cp16(gB + k0 + (size_t)16 * K,     lB + 16 * 64);
        async_cp16(gB + k0 + (size_t)24 * K,     lB + 24 * 64);
        __syncthreads();

#pragma unroll
        for (int kk = 0; kk < 2; ++kk) {
            const int lc = quad + kk * 4;   // logical 16B chunk
            short8 af[4], bf[4];
#pragma unroll
            for (int mt = 0; mt < 4; ++mt)
                af[mt] = *(const short8*)&sA[(mrow + mt * 16 + l16) * 64 + (lc ^ fs) * 8];
#pragma unroll
            for (int nt = 0; nt < 4; ++nt)
                bf[nt] = *(const short8*)&sB[(ncol + nt * 16 + l16) * 64 + (lc ^ fs) * 8];
#pragma unroll
            for (int mt = 0; mt < 4; ++mt)
#pragma unroll
                for (int nt = 0; nt < 4; ++nt)
                    acc[mt][nt] = __builtin_amdgcn_mfma_f32_16x16x32_bf16(af[mt], bf[nt], acc[mt][nt], 0, 0, 0);
        }
    }

#pragma unroll
    for (int nt = 0; nt < 4; ++nt) {
        int col = colBase + ncol + nt * 16 + l16;
        float bv = bias[col];
#pragma unroll
        for (int mt = 0; mt < 4; ++mt) {
#pragma unroll
            for (int r = 0; r < 4; ++r) {
                int row = rowBase + mrow + mt * 16 + quad * 4 + r;
                O[(size_t)row * DM + col] = (OutT)(acc[mt][nt][r] + bv);
            }
        }
    }
}

// 128x64-tile GEMM for Wo: round-7 proven BK=32 version (12 KB LDS, 512 blocks).
template <typename OutT>
__global__ __launch_bounds__(256) void gemm_n64(
    const __hip_bfloat16* __restrict__ A,
    const __hip_bfloat16* __restrict__ B,
    const float* __restrict__ bias,
    OutT* __restrict__ O)
{
    const int K = DM;
    __shared__ __align__(16) unsigned short sA[128 * 32];
    __shared__ __align__(16) unsigned short sB[64 * 32];

    const int tid  = threadIdx.x;
    const int w    = tid >> 6;
    const int lane = tid & 63;
    const int l16  = lane & 15;
    const int quad = lane >> 4;
    const int rowBase = blockIdx.x * 128;
    const int colBase = blockIdx.y * 64;

    const int srow   = lane >> 2;
    const int sswz   = (srow & 3) ^ (srow >> 2);
    const int gchunk = (lane & 3) ^ sswz;
    const __hip_bfloat16* gA = A + (size_t)(rowBase + w * 32 + srow) * K + gchunk * 8;
    const __hip_bfloat16* gB = B + (size_t)(colBase + w * 16 + srow) * K + gchunk * 8;
    unsigned short* lA = sA + w * 32 * 32;
    unsigned short* lB = sB + w * 16 * 32;

    const int fswz = (l16 & 3) ^ (l16 >> 2);
    const int mrow = w * 32;

    f32x4 acc[2][4];
#pragma unroll
    for (int i = 0; i < 2; ++i)
#pragma unroll
        for (int j = 0; j < 4; ++j) acc[i][j] = (f32x4){0.f, 0.f, 0.f, 0.f};

    for (int k0 = 0; k0 < K; k0 += 32) {
        __syncthreads();
        async_cp16(gA + k0, lA);
        async_cp16(gA + k0 + (size_t)16 * K, lA + 16 * 32);
        async_cp16(gB + k0, lB);
        __syncthreads();

        short8 af[2], bf[4];
#pragma unroll
        for (int mt = 0; mt < 2; ++mt)
            af[mt] = *(const short8*)&sA[(mrow + mt * 16 + l16) * 32 + (quad ^ fswz) * 8];
#pragma unroll
        for (int nt = 0; nt < 4; ++nt)
            bf[nt] = *(const short8*)&sB[(nt * 16 + l16) * 32 + (quad ^ fswz) * 8];
#pragma unroll
        for (int mt = 0; mt < 2; ++mt)
#pragma unroll
            for (int nt = 0; nt < 4; ++nt)
                acc[mt][nt] = __builtin_amdgcn_mfma_f32_16x16x32_bf16(af[mt], bf[nt], acc[mt][nt], 0, 0, 0);
    }

#pragma unroll
    for (int nt = 0; nt < 4; ++nt) {
        int col = colBase + nt * 16 + l16;
        float bv = bias[col];
#pragma unroll
        for (int mt = 0; mt < 2; ++mt) {
#pragma unroll
            for (int r = 0; r < 4; ++r) {
                int row = rowBase + mrow + mt * 16 + quad * 4 + r;
                O[(size_t)row * DM + col] = (OutT)(acc[mt][nt][r] + bv);
            }
        }
    }
}

// Merged aux kernel: blocks 0..511 = chunk means; blocks 512..575 = gate GEMM.
__global__ __launch_bounds__(256) void aux_kernel(
    const __hip_bfloat16* __restrict__ K,
    const __hip_bfloat16* __restrict__ V,
    __hip_bfloat16* __restrict__ CK,
    __hip_bfloat16* __restrict__ CV,
    const __hip_bfloat16* __restrict__ xb,
    const __hip_bfloat16* __restrict__ Wgb,
    const float* __restrict__ bg,
    float* __restrict__ G)
{
    const int b = blockIdx.x;
    if (b < 512) {
        const int c = b >> 2;
        const int d = (b & 3) * 256 + threadIdx.x;
        float ak = 0.f, av = 0.f;
        for (int i = 0; i < 32; ++i) {
            ak += (float)K[(size_t)(c * 32 + i) * DM + d];
            av += (float)V[(size_t)(c * 32 + i) * DM + d];
        }
        CK[(size_t)c * DM + d] = (__hip_bfloat16)(ak * (1.f / 32.f));
        CV[(size_t)c * DM + d] = (__hip_bfloat16)(av * (1.f / 32.f));
    } else {
        const int w    = threadIdx.x >> 6;
        const int lane = threadIdx.x & 63;
        const int l16  = lane & 15;
        const int quad = lane >> 4;
        const int t0   = ((b - 512) * 4 + w) * 16;
        const __hip_bfloat16* ap = xb + (size_t)(t0 + l16) * DM + quad * 8;
        const __hip_bfloat16* bp = Wgb + (size_t)l16 * DM + quad * 8;
        f32x4 acc = (f32x4){0.f, 0.f, 0.f, 0.f};
#pragma unroll 4
        for (int k0 = 0; k0 < DM; k0 += 32) {
            short8 a = *(const short8*)(ap + k0);
            short8 bb = *(const short8*)(bp + k0);
            acc = __builtin_amdgcn_mfma_f32_16x16x32_bf16(a, bb, acc, 0, 0, 0);
        }
        float bgv = bg[l16];
#pragma unroll
        for (int r = 0; r < 4; ++r) {
            int t = t0 + quad * 4 + r;
            float z = acc[r] + bgv;
            G[t * NH + l16] = 1.f / (1.f + __expf(-z));
        }
    }
}

// MFMA attention: 64 queries x 1 head per block (grid 64 x 16, 256 threads).
__global__ __launch_bounds__(256) void attn_mfma(
    const __hip_bfloat16* __restrict__ Q,
    const __hip_bfloat16* __restrict__ K,
    const __hip_bfloat16* __restrict__ V,
    const __hip_bfloat16* __restrict__ CK,
    const __hip_bfloat16* __restrict__ CV,
    const float* __restrict__ G,
    __hip_bfloat16* __restrict__ Aout)
{
    __shared__ alignas(16) unsigned short Pls[64 * PSTR];
    __shared__ alignas(16) unsigned short Vts[64 * PSTR];

    const int h   = blockIdx.y;
    const int t0  = blockIdx.x * 64;
    const int tid = threadIdx.x;
    const int w    = tid >> 6;
    const int lane = tid & 63;
    const int l16  = lane & 15;
    const int quad = lane >> 4;
    const float scale = 0.125f;

    const int rc0  = (t0 >= 96) ? ((t0 - 64) >> 5) : 0;
    const int cmin = rc0 > 16 ? rc0 - 16 : 0;

    const unsigned short* Vu  = (const unsigned short*)V;
    const unsigned short* CVu = (const unsigned short*)CV;

    // stage V^T (+ CV^T) into LDS via 16B row-chunk loads + packed ushort2 writes
    {
#pragma unroll
        for (int gg = 0; gg < 2; ++gg) {
            const int g = w * 2 + gg;
#pragma unroll
            for (int i = 0; i < 2; ++i) {
                const int pair = lane + 64 * i;
                if (pair < 80) {
                    const int j = pair * 2;
                    const unsigned short *s0, *s1;
                    if (j < 128) {
                        int tok0 = t0 - 64 + j; if (tok0 < 0) tok0 = 0;
                        int tok1 = t0 - 63 + j; if (tok1 < 0) tok1 = 0;
                        s0 = Vu + (size_t)tok0 * DM + h * 64 + g * 8;
                        s1 = Vu + (size_t)tok1 * DM + h * 64 + g * 8;
                    } else {
                        int c0 = cmin + (j - 128); if (c0 > 127) c0 = 127;
                        int c1 = c0 + 1;           if (c1 > 127) c1 = 127;
                        s0 = CVu + (size_t)c0 * DM + h * 64 + g * 8;
                        s1 = CVu + (size_t)c1 * DM + h * 64 + g * 8;
                    }
                    short8 v0 = *(const short8*)s0;
                    short8 v1 = *(const short8*)s1;
#pragma unroll
                    for (int e = 0; e < 8; ++e) {
                        ushort2 pk;
                        pk.x = (unsigned short)v0[e];
                        pk.y = (unsigned short)v1[e];
                        *(ushort2*)&Vts[(g * 8 + e) * PSTR + j] = pk;
                    }
                }
            }
        }
    }

    const __hip_bfloat16* qp = Q + (size_t)(t0 + w * 16 + l16) * DM + h * 64 + quad * 8;
    short8 qf0 = *(const short8*)(qp);
    short8 qf1 = *(const short8*)(qp + 32);

    f32x4 sc[8];
#pragma unroll
    for (int jt = 0; jt < 8; ++jt) {
        int j = jt * 16 + l16;
        int tok = t0 - 64 + j;
        tok = tok < 0 ? 0 : tok;
        const __hip_bfloat16* kp = K + (size_t)tok * DM + h * 64 + quad * 8;
        short8 b0 = *(const short8*)(kp);
        short8 b1 = *(const short8*)(kp + 32);
        f32x4 a = __builtin_amdgcn_mfma_f32_16x16x32_bf16(qf0, b0, (f32x4){0.f,0.f,0.f,0.f}, 0, 0, 0);
        sc[jt]  = __builtin_amdgcn_mfma_f32_16x16x32_bf16(qf1, b1, a, 0, 0, 0);
    }
    f32x4 sc2[2];
#pragma unroll
    for (int jt = 0; jt < 2; ++jt) {
        int c = cmin + jt * 16 + l16;
        if (c > 127) c = 127;
        const __hip_bfloat16* cp = CK + (size_t)c * DM + h * 64 + quad * 8;
        short8 b0 = *(const short8*)(cp);
        short8 b1 = *(const short8*)(cp + 32);
        f32x4 a = __builtin_amdgcn_mfma_f32_16x16x32_bf16(qf0, b0, (f32x4){0.f,0.f,0.f,0.f}, 0, 0, 0);
        sc2[jt] = __builtin_amdgcn_mfma_f32_16x16x32_bf16(qf1, b1, a, 0, 0, 0);
    }

    __syncthreads();

    const int rbase = w * 16 + quad * 4;
    float gl[4], g2[4];
    float mx[4], sm[4], mx2[4], sm2[4];
#pragma unroll
    for (int reg = 0; reg < 4; ++reg) {
        int rr = rbase + reg;
        int t  = t0 + rr;
        float g = G[t * NH + h];
        int rc = (t >= 96) ? ((t - 64) >> 5) : 0;
        gl[reg] = (t > 0)  ? g        : 0.f;
        g2[reg] = (rc > 0) ? (1.f - g) : 0.f;

        int jlo = rr > (64 - t0) ? rr : (64 - t0);
        int jhi = rr + 63;
        float m = -1e30f;
#pragma unroll
        for (int jt = 0; jt < 8; ++jt) {
            int j = jt * 16 + l16;
            float s = (j >= jlo && j <= jhi) ? sc[jt][reg] * scale : -1e30f;
            sc[jt][reg] = s;
            m = fmaxf(m, s);
        }
        mx[reg] = m;

        int nvis = rc < 16 ? rc : 16;
        int clo = rc - nvis, chi = rc - 1;
        float m2 = -1e30f;
#pragma unroll
        for (int jt = 0; jt < 2; ++jt) {
            int c = cmin + jt * 16 + l16;
            float s = (c >= clo && c <= chi) ? sc2[jt][reg] * scale : -1e30f;
            sc2[jt][reg] = s;
            m2 = fmaxf(m2, s);
        }
        mx2[reg] = m2;
    }
#pragma unroll
    for (int off = 1; off <= 8; off <<= 1)
#pragma unroll
        for (int reg = 0; reg < 4; ++reg) {
            mx[reg]  = fmaxf(mx[reg],  __shfl_xor(mx[reg],  off));
            mx2[reg] = fmaxf(mx2[reg], __shfl_xor(mx2[reg], off));
        }
#pragma unroll
    for (int reg = 0; reg < 4; ++reg) {
        float s = 0.f, s2 = 0.f;
#pragma unroll
        for (int jt = 0; jt < 8; ++jt) {
            float p = __expf(sc[jt][reg] - mx[reg]);
            sc[jt][reg] = p;
            s += p;
        }
#pragma unroll
        for (int jt = 0; jt < 2; ++jt) {
            float p = __expf(sc2[jt][reg] - mx2[reg]);
            sc2[jt][reg] = p;
            s2 += p;
        }
        sm[reg] = s; sm2[reg] = s2;
    }
#pragma unroll
    for (int off = 1; off <= 8; off <<= 1)
#pragma unroll
        for (int reg = 0; reg < 4; ++reg) {
            sm[reg]  += __shfl_xor(sm[reg],  off);
            sm2[reg] += __shfl_xor(sm2[reg], off);
        }

#pragma unroll
    for (int reg = 0; reg < 4; ++reg) {
        float f1 = gl[reg] / sm[reg];
        float f2 = g2[reg] / sm2[reg];
        int rowoff = (rbase + reg) * PSTR;
#pragma unroll
        for (int jt = 0; jt < 8; ++jt) {
            __hip_bfloat16 hb = (__hip_bfloat16)(sc[jt][reg] * f1);
            Pls[rowoff + jt * 16 + l16] = *(unsigned short*)&hb;
        }
#pragma unroll
        for (int jt = 0; jt < 2; ++jt) {
            __hip_bfloat16 hb = (__hip_bfloat16)(sc2[jt][reg] * f2);
            Pls[rowoff + 128 + jt * 16 + l16] = *(unsigned short*)&hb;
        }
    }
    asm volatile("s_waitcnt lgkmcnt(0)" ::: "memory");  // wave-private P round-trip

    f32x4 o[4];
#pragma unroll
    for (int nt = 0; nt < 4; ++nt) o[nt] = (f32x4){0.f, 0.f, 0.f, 0.f};
#pragma unroll
    for (int kt = 0; kt < 5; ++kt) {
        short8 a = *(const short8*)&Pls[(w * 16 + l16) * PSTR + kt * 32 + quad * 8];
#pragma unroll
        for (int nt = 0; nt < 4; ++nt) {
            int dd = nt * 16 + l16;
            short8 b = *(const short8*)&Vts[dd * PSTR + kt * 32 + quad * 8];
            o[nt] = __builtin_amdgcn_mfma_f32_16x16x32_bf16(a, b, o[nt], 0, 0, 0);
        }
    }

#pragma unroll
    for (int nt = 0; nt < 4; ++nt) {
#pragma unroll
        for (int reg = 0; reg < 4; ++reg) {
            int row = t0 + rbase + reg;
            int col = h * 64 + nt * 16 + l16;
            Aout[(size_t)row * DM + col] = (__hip_bfloat16)(o[nt][reg]);
        }
    }
}

extern "C" void kernel_launch(void* const* d_in, const int* in_sizes, int n_in,
                              void* d_out, int out_size, void* d_ws, size_t ws_size,
                              hipStream_t stream)
{
    const float* x  = (const float*)d_in[0];
    const float* Wq = (const float*)d_in[1];
    const float* bq = (const float*)d_in[2];
    const float* Wk = (const float*)d_in[3];
    const float* bk = (const float*)d_in[4];
    const float* Wv = (const float*)d_in[5];
    const float* bv = (const float*)d_in[6];
    const float* Wo = (const float*)d_in[7];
    const float* bo = (const float*)d_in[8];
    const float* Wg = (const float*)d_in[9];
    const float* bg = (const float*)d_in[10];
    float* out = (float*)d_out;

    char* ws = (char*)d_ws;
    const size_t MB = 1024 * 1024;
    __hip_bfloat16* xb  = (__hip_bfloat16*)(ws + 0 * MB);   // 8 MB
    __hip_bfloat16* Qb  = (__hip_bfloat16*)(ws + 8 * MB);   // 8 MB
    __hip_bfloat16* Kb  = (__hip_bfloat16*)(ws + 16 * MB);  // 8 MB
    __hip_bfloat16* Vb  = (__hip_bfloat16*)(ws + 24 * MB);  // 8 MB
    __hip_bfloat16* Ab  = (__hip_bfloat16*)(ws + 32 * MB);  // 8 MB
    __hip_bfloat16* Wqb = (__hip_bfloat16*)(ws + 40 * MB);  // 2 MB
    __hip_bfloat16* Wkb = (__hip_bfloat16*)(ws + 42 * MB);  // 2 MB
    __hip_bfloat16* Wvb = (__hip_bfloat16*)(ws + 44 * MB);  // 2 MB
    __hip_bfloat16* Wob = (__hip_bfloat16*)(ws + 46 * MB);  // 2 MB
    __hip_bfloat16* CKb = (__hip_bfloat16*)(ws + 48 * MB);            // 256 KB
    __hip_bfloat16* CVb = (__hip_bfloat16*)(ws + 48 * MB + 256*1024); // 256 KB
    float* Gf           = (float*)(ws + 48 * MB + 512 * 1024);        // 256 KB
    __hip_bfloat16* Wgb = (__hip_bfloat16*)(ws + 48 * MB + 768*1024); // 32 KB

    cast_all<<<dim3(8208), 256, 0, stream>>>(x, Wq, Wk, Wv, Wo, Wg,
                                             xb, Wqb, Wkb, Wvb, Wob, Wgb);

    // Fused QKV GEMM: grid (32, 24); group = blockIdx.y>>3.
    gemm128<__hip_bfloat16><<<dim3(32, 24), 256, 0, stream>>>(
        xb, Wqb, Wkb, Wvb, bq, bk, bv, Qb, Kb, Vb);
    // Merged chunk-means + gate GEMM.
    aux_kernel<<<dim3(576), 256, 0, stream>>>(Kb, Vb, CKb, CVb, xb, Wgb, bg, Gf);
    attn_mfma<<<dim3(64, 16), 256, 0, stream>>>(Qb, Kb, Vb, CKb, CVb, Gf, Ab);
    // Output GEMM: 128x64 tiles (BK=32, round-7 proven), grid (32, 16).
    gemm_n64<float><<<dim3(32, 16), 256, 0, stream>>>(Ab, Wob, bo, out);
}

// Round 10
// 179.449 us; speedup vs baseline: 1.0328x; 1.0328x over previous
//
#include <hip/hip_runtime.h>
#include <hip/hip_bf16.h>
#include <math.h>

typedef __attribute__((ext_vector_type(8))) short short8;
typedef __attribute__((ext_vector_type(4))) float f32x4;

#define TT 4096
#define DM 1024
#define NH 16
#define HD 64
#define PSTR 168   // attn LDS row stride in halfwords (84 dwords == 20 mod 32 banks)

typedef __attribute__((address_space(3))) unsigned int lds_u32;
typedef __attribute__((address_space(1))) unsigned int glb_u32;

__device__ __forceinline__ void async_cp16(const void* g, void* l) {
    __builtin_amdgcn_global_load_lds((glb_u32*)g, (lds_u32*)l, 16, 0, 0);
}

// Fused fp32 -> bf16 cast for x + Wq/Wk/Wv/Wo + Wg.
__global__ __launch_bounds__(256) void cast_all(
    const float* __restrict__ x,  const float* __restrict__ wq,
    const float* __restrict__ wk, const float* __restrict__ wv,
    const float* __restrict__ wo, const float* __restrict__ wg,
    __hip_bfloat16* __restrict__ xb,  __hip_bfloat16* __restrict__ wqb,
    __hip_bfloat16* __restrict__ wkb, __hip_bfloat16* __restrict__ wvb,
    __hip_bfloat16* __restrict__ wob, __hip_bfloat16* __restrict__ wgb)
{
    int b = blockIdx.x;
    const float* src;
    __hip_bfloat16* dst;
    size_t base;
    if (b < 4096)      { src = x;  dst = xb;  base = (size_t)b * 1024; }
    else if (b < 5120) { src = wq; dst = wqb; base = (size_t)(b - 4096) * 1024; }
    else if (b < 6144) { src = wk; dst = wkb; base = (size_t)(b - 5120) * 1024; }
    else if (b < 7168) { src = wv; dst = wvb; base = (size_t)(b - 6144) * 1024; }
    else if (b < 8192) { src = wo; dst = wob; base = (size_t)(b - 7168) * 1024; }
    else               { src = wg; dst = wgb; base = (size_t)(b - 8192) * 1024; }
    size_t i = base + (size_t)threadIdx.x * 4;
    float4 v = *(const float4*)(src + i);
    __hip_bfloat16 h0 = (__hip_bfloat16)v.x;
    __hip_bfloat16 h1 = (__hip_bfloat16)v.y;
    __hip_bfloat16 h2 = (__hip_bfloat16)v.z;
    __hip_bfloat16 h3 = (__hip_bfloat16)v.w;
    ushort4 u;
    u.x = *(unsigned short*)&h0;
    u.y = *(unsigned short*)&h1;
    u.z = *(unsigned short*)&h2;
    u.w = *(unsigned short*)&h3;
    *(ushort4*)((unsigned short*)dst + i) = u;
}

// 128x128-tile GEMM, BK=32 single-buffered (round-7 proven structure; BK=64
// regressed +9us -- DMA-latency per barrier interval dominates, not barrier
// count). Fused QKV via group = blockIdx.y>>3. For K/V groups the epilogue
// also emits 32-token chunk means (CK/CV) from the fp32 accumulators:
// sum 4 regs + shfl_xor(16,32) across quads = 32-row column sum in-register.
template <typename OutT>
__global__ __launch_bounds__(256) void gemm128(
    const __hip_bfloat16* __restrict__ A,
    const __hip_bfloat16* __restrict__ B0, const __hip_bfloat16* __restrict__ B1,
    const __hip_bfloat16* __restrict__ B2,
    const float* __restrict__ c0, const float* __restrict__ c1, const float* __restrict__ c2,
    OutT* __restrict__ O0, OutT* __restrict__ O1, OutT* __restrict__ O2,
    __hip_bfloat16* __restrict__ CK, __hip_bfloat16* __restrict__ CV)
{
    const int K = DM;
    __shared__ __align__(16) unsigned short sA[128 * 32];
    __shared__ __align__(16) unsigned short sB[128 * 32];

    const int grp = blockIdx.y >> 3;
    const __hip_bfloat16* B = grp == 0 ? B0 : (grp == 1 ? B1 : B2);
    const float* bias       = grp == 0 ? c0 : (grp == 1 ? c1 : c2);
    OutT* O                 = grp == 0 ? O0 : (grp == 1 ? O1 : O2);

    const int tid  = threadIdx.x;
    const int w    = tid >> 6;
    const int lane = tid & 63;
    const int l16  = lane & 15;
    const int quad = lane >> 4;
    const int rowBase = blockIdx.x * 128;
    const int colBase = (blockIdx.y & 7) * 128;

    const int srow   = lane >> 2;
    const int sswz   = (srow & 3) ^ (srow >> 2);
    const int gchunk = (lane & 3) ^ sswz;
    const __hip_bfloat16* gA = A + (size_t)(rowBase + w * 32 + srow) * K + gchunk * 8;
    const __hip_bfloat16* gB = B + (size_t)(colBase + w * 32 + srow) * K + gchunk * 8;
    unsigned short* lA = sA + w * 32 * 32;
    unsigned short* lB = sB + w * 32 * 32;

    const int fswz = (l16 & 3) ^ (l16 >> 2);
    const int mrow = (w & 1) * 64;
    const int ncol = (w >> 1) * 64;

    f32x4 acc[4][4];
#pragma unroll
    for (int i = 0; i < 4; ++i)
#pragma unroll
        for (int j = 0; j < 4; ++j) acc[i][j] = (f32x4){0.f, 0.f, 0.f, 0.f};

    for (int k0 = 0; k0 < K; k0 += 32) {
        __syncthreads();
        async_cp16(gA + k0, lA);
        async_cp16(gA + k0 + (size_t)16 * K, lA + 16 * 32);
        async_cp16(gB + k0, lB);
        async_cp16(gB + k0 + (size_t)16 * K, lB + 16 * 32);
        __syncthreads();

        short8 af[4], bf[4];
#pragma unroll
        for (int mt = 0; mt < 4; ++mt)
            af[mt] = *(const short8*)&sA[(mrow + mt * 16 + l16) * 32 + (quad ^ fswz) * 8];
#pragma unroll
        for (int nt = 0; nt < 4; ++nt)
            bf[nt] = *(const short8*)&sB[(ncol + nt * 16 + l16) * 32 + (quad ^ fswz) * 8];
#pragma unroll
        for (int mt = 0; mt < 4; ++mt)
#pragma unroll
            for (int nt = 0; nt < 4; ++nt)
                acc[mt][nt] = __builtin_amdgcn_mfma_f32_16x16x32_bf16(af[mt], bf[nt], acc[mt][nt], 0, 0, 0);
    }

#pragma unroll
    for (int nt = 0; nt < 4; ++nt) {
        int col = colBase + ncol + nt * 16 + l16;
        float bv = bias[col];
#pragma unroll
        for (int mt = 0; mt < 4; ++mt) {
#pragma unroll
            for (int r = 0; r < 4; ++r) {
                int row = rowBase + mrow + mt * 16 + quad * 4 + r;
                O[(size_t)row * DM + col] = (OutT)(acc[mt][nt][r] + bv);
            }
        }
    }

    // chunk means for K/V groups: wave covers rows rowBase+mrow..+63 (2 chunks)
    // x cols colBase+ncol..+63 -- (chunk, col) unique per wave, no collisions.
    if (grp != 0) {
        __hip_bfloat16* CC = (grp == 1) ? CK : CV;
#pragma unroll
        for (int half = 0; half < 2; ++half) {
#pragma unroll
            for (int nt = 0; nt < 4; ++nt) {
                float s = 0.f;
#pragma unroll
                for (int mt = half * 2; mt < half * 2 + 2; ++mt)
#pragma unroll
                    for (int r = 0; r < 4; ++r) s += acc[mt][nt][r];
                s += __shfl_xor(s, 16);
                s += __shfl_xor(s, 32);
                if (quad == 0) {
                    int chunk = (rowBase + mrow) / 32 + half;
                    int col = colBase + ncol + nt * 16 + l16;
                    CC[(size_t)chunk * DM + col] =
                        (__hip_bfloat16)(s * (1.f / 32.f) + bias[col]);
                }
            }
        }
    }
}

// 128x64-tile GEMM for Wo (BK=32, round-7 proven; 12 KB LDS, 512 blocks).
template <typename OutT>
__global__ __launch_bounds__(256) void gemm_n64(
    const __hip_bfloat16* __restrict__ A,
    const __hip_bfloat16* __restrict__ B,
    const float* __restrict__ bias,
    OutT* __restrict__ O)
{
    const int K = DM;
    __shared__ __align__(16) unsigned short sA[128 * 32];
    __shared__ __align__(16) unsigned short sB[64 * 32];

    const int tid  = threadIdx.x;
    const int w    = tid >> 6;
    const int lane = tid & 63;
    const int l16  = lane & 15;
    const int quad = lane >> 4;
    const int rowBase = blockIdx.x * 128;
    const int colBase = blockIdx.y * 64;

    const int srow   = lane >> 2;
    const int sswz   = (srow & 3) ^ (srow >> 2);
    const int gchunk = (lane & 3) ^ sswz;
    const __hip_bfloat16* gA = A + (size_t)(rowBase + w * 32 + srow) * K + gchunk * 8;
    const __hip_bfloat16* gB = B + (size_t)(colBase + w * 16 + srow) * K + gchunk * 8;
    unsigned short* lA = sA + w * 32 * 32;
    unsigned short* lB = sB + w * 16 * 32;

    const int fswz = (l16 & 3) ^ (l16 >> 2);
    const int mrow = w * 32;

    f32x4 acc[2][4];
#pragma unroll
    for (int i = 0; i < 2; ++i)
#pragma unroll
        for (int j = 0; j < 4; ++j) acc[i][j] = (f32x4){0.f, 0.f, 0.f, 0.f};

    for (int k0 = 0; k0 < K; k0 += 32) {
        __syncthreads();
        async_cp16(gA + k0, lA);
        async_cp16(gA + k0 + (size_t)16 * K, lA + 16 * 32);
        async_cp16(gB + k0, lB);
        __syncthreads();

        short8 af[2], bf[4];
#pragma unroll
        for (int mt = 0; mt < 2; ++mt)
            af[mt] = *(const short8*)&sA[(mrow + mt * 16 + l16) * 32 + (quad ^ fswz) * 8];
#pragma unroll
        for (int nt = 0; nt < 4; ++nt)
            bf[nt] = *(const short8*)&sB[(nt * 16 + l16) * 32 + (quad ^ fswz) * 8];
#pragma unroll
        for (int mt = 0; mt < 2; ++mt)
#pragma unroll
            for (int nt = 0; nt < 4; ++nt)
                acc[mt][nt] = __builtin_amdgcn_mfma_f32_16x16x32_bf16(af[mt], bf[nt], acc[mt][nt], 0, 0, 0);
    }

#pragma unroll
    for (int nt = 0; nt < 4; ++nt) {
        int col = colBase + nt * 16 + l16;
        float bv = bias[col];
#pragma unroll
        for (int mt = 0; mt < 2; ++mt) {
#pragma unroll
            for (int r = 0; r < 4; ++r) {
                int row = rowBase + mrow + mt * 16 + quad * 4 + r;
                O[(size_t)row * DM + col] = (OutT)(acc[mt][nt][r] + bv);
            }
        }
    }
}

// Gate GEMM via MFMA: G[t,h] = sigmoid(xb[t,:] . Wgb[h,:] + bg[h]).
// 64 blocks x 4 waves; one wave per 16-token tile.
__global__ __launch_bounds__(256) void g_mfma(
    const __hip_bfloat16* __restrict__ xb,
    const __hip_bfloat16* __restrict__ Wgb,
    const float* __restrict__ bg,
    float* __restrict__ G)
{
    const int w    = threadIdx.x >> 6;
    const int lane = threadIdx.x & 63;
    const int l16  = lane & 15;
    const int quad = lane >> 4;
    const int t0   = (blockIdx.x * 4 + w) * 16;
    const __hip_bfloat16* ap = xb + (size_t)(t0 + l16) * DM + quad * 8;
    const __hip_bfloat16* bp = Wgb + (size_t)l16 * DM + quad * 8;
    f32x4 acc = (f32x4){0.f, 0.f, 0.f, 0.f};
#pragma unroll 4
    for (int k0 = 0; k0 < DM; k0 += 32) {
        short8 a = *(const short8*)(ap + k0);
        short8 b = *(const short8*)(bp + k0);
        acc = __builtin_amdgcn_mfma_f32_16x16x32_bf16(a, b, acc, 0, 0, 0);
    }
    float bgv = bg[l16];
#pragma unroll
    for (int r = 0; r < 4; ++r) {
        int t = t0 + quad * 4 + r;
        float z = acc[r] + bgv;
        G[t * NH + l16] = 1.f / (1.f + __expf(-z));
    }
}

// MFMA attention: 64 queries x 1 head per block (grid 64 x 16, 256 threads).
__global__ __launch_bounds__(256) void attn_mfma(
    const __hip_bfloat16* __restrict__ Q,
    const __hip_bfloat16* __restrict__ K,
    const __hip_bfloat16* __restrict__ V,
    const __hip_bfloat16* __restrict__ CK,
    const __hip_bfloat16* __restrict__ CV,
    const float* __restrict__ G,
    __hip_bfloat16* __restrict__ Aout)
{
    __shared__ alignas(16) unsigned short Pls[64 * PSTR];
    __shared__ alignas(16) unsigned short Vts[64 * PSTR];

    const int h   = blockIdx.y;
    const int t0  = blockIdx.x * 64;
    const int tid = threadIdx.x;
    const int w    = tid >> 6;
    const int lane = tid & 63;
    const int l16  = lane & 15;
    const int quad = lane >> 4;
    const float scale = 0.125f;

    const int rc0  = (t0 >= 96) ? ((t0 - 64) >> 5) : 0;
    const int cmin = rc0 > 16 ? rc0 - 16 : 0;

    const unsigned short* Vu  = (const unsigned short*)V;
    const unsigned short* CVu = (const unsigned short*)CV;

    // stage V^T (+ CV^T) into LDS via 16B row-chunk loads + packed ushort2 writes
    {
#pragma unroll
        for (int gg = 0; gg < 2; ++gg) {
            const int g = w * 2 + gg;
#pragma unroll
            for (int i = 0; i < 2; ++i) {
                const int pair = lane + 64 * i;
                if (pair < 80) {
                    const int j = pair * 2;
                    const unsigned short *s0, *s1;
                    if (j < 128) {
                        int tok0 = t0 - 64 + j; if (tok0 < 0) tok0 = 0;
                        int tok1 = t0 - 63 + j; if (tok1 < 0) tok1 = 0;
                        s0 = Vu + (size_t)tok0 * DM + h * 64 + g * 8;
                        s1 = Vu + (size_t)tok1 * DM + h * 64 + g * 8;
                    } else {
                        int c0 = cmin + (j - 128); if (c0 > 127) c0 = 127;
                        int c1 = c0 + 1;           if (c1 > 127) c1 = 127;
                        s0 = CVu + (size_t)c0 * DM + h * 64 + g * 8;
                        s1 = CVu + (size_t)c1 * DM + h * 64 + g * 8;
                    }
                    short8 v0 = *(const short8*)s0;
                    short8 v1 = *(const short8*)s1;
#pragma unroll
                    for (int e = 0; e < 8; ++e) {
                        ushort2 pk;
                        pk.x = (unsigned short)v0[e];
                        pk.y = (unsigned short)v1[e];
                        *(ushort2*)&Vts[(g * 8 + e) * PSTR + j] = pk;
                    }
                }
            }
        }
    }

    const __hip_bfloat16* qp = Q + (size_t)(t0 + w * 16 + l16) * DM + h * 64 + quad * 8;
    short8 qf0 = *(const short8*)(qp);
    short8 qf1 = *(const short8*)(qp + 32);

    f32x4 sc[8];
#pragma unroll
    for (int jt = 0; jt < 8; ++jt) {
        int j = jt * 16 + l16;
        int tok = t0 - 64 + j;
        tok = tok < 0 ? 0 : tok;
        const __hip_bfloat16* kp = K + (size_t)tok * DM + h * 64 + quad * 8;
        short8 b0 = *(const short8*)(kp);
        short8 b1 = *(const short8*)(kp + 32);
        f32x4 a = __builtin_amdgcn_mfma_f32_16x16x32_bf16(qf0, b0, (f32x4){0.f,0.f,0.f,0.f}, 0, 0, 0);
        sc[jt]  = __builtin_amdgcn_mfma_f32_16x16x32_bf16(qf1, b1, a, 0, 0, 0);
    }
    f32x4 sc2[2];
#pragma unroll
    for (int jt = 0; jt < 2; ++jt) {
        int c = cmin + jt * 16 + l16;
        if (c > 127) c = 127;
        const __hip_bfloat16* cp = CK + (size_t)c * DM + h * 64 + quad * 8;
        short8 b0 = *(const short8*)(cp);
        short8 b1 = *(const short8*)(cp + 32);
        f32x4 a = __builtin_amdgcn_mfma_f32_16x16x32_bf16(qf0, b0, (f32x4){0.f,0.f,0.f,0.f}, 0, 0, 0);
        sc2[jt] = __builtin_amdgcn_mfma_f32_16x16x32_bf16(qf1, b1, a, 0, 0, 0);
    }

    __syncthreads();

    const int rbase = w * 16 + quad * 4;
    float gl[4], g2[4];
    float mx[4], sm[4], mx2[4], sm2[4];
#pragma unroll
    for (int reg = 0; reg < 4; ++reg) {
        int rr = rbase + reg;
        int t  = t0 + rr;
        float g = G[t * NH + h];
        int rc = (t >= 96) ? ((t - 64) >> 5) : 0;
        gl[reg] = (t > 0)  ? g        : 0.f;
        g2[reg] = (rc > 0) ? (1.f - g) : 0.f;

        int jlo = rr > (64 - t0) ? rr : (64 - t0);
        int jhi = rr + 63;
        float m = -1e30f;
#pragma unroll
        for (int jt = 0; jt < 8; ++jt) {
            int j = jt * 16 + l16;
            float s = (j >= jlo && j <= jhi) ? sc[jt][reg] * scale : -1e30f;
            sc[jt][reg] = s;
            m = fmaxf(m, s);
        }
        mx[reg] = m;

        int nvis = rc < 16 ? rc : 16;
        int clo = rc - nvis, chi = rc - 1;
        float m2 = -1e30f;
#pragma unroll
        for (int jt = 0; jt < 2; ++jt) {
            int c = cmin + jt * 16 + l16;
            float s = (c >= clo && c <= chi) ? sc2[jt][reg] * scale : -1e30f;
            sc2[jt][reg] = s;
            m2 = fmaxf(m2, s);
        }
        mx2[reg] = m2;
    }
#pragma unroll
    for (int off = 1; off <= 8; off <<= 1)
#pragma unroll
        for (int reg = 0; reg < 4; ++reg) {
            mx[reg]  = fmaxf(mx[reg],  __shfl_xor(mx[reg],  off));
            mx2[reg] = fmaxf(mx2[reg], __shfl_xor(mx2[reg], off));
        }
#pragma unroll
    for (int reg = 0; reg < 4; ++reg) {
        float s = 0.f, s2 = 0.f;
#pragma unroll
        for (int jt = 0; jt < 8; ++jt) {
            float p = __expf(sc[jt][reg] - mx[reg]);
            sc[jt][reg] = p;
            s += p;
        }
#pragma unroll
        for (int jt = 0; jt < 2; ++jt) {
            float p = __expf(sc2[jt][reg] - mx2[reg]);
            sc2[jt][reg] = p;
            s2 += p;
        }
        sm[reg] = s; sm2[reg] = s2;
    }
#pragma unroll
    for (int off = 1; off <= 8; off <<= 1)
#pragma unroll
        for (int reg = 0; reg < 4; ++reg) {
            sm[reg]  += __shfl_xor(sm[reg],  off);
            sm2[reg] += __shfl_xor(sm2[reg], off);
        }

#pragma unroll
    for (int reg = 0; reg < 4; ++reg) {
        float f1 = gl[reg] / sm[reg];
        float f2 = g2[reg] / sm2[reg];
        int rowoff = (rbase + reg) * PSTR;
#pragma unroll
        for (int jt = 0; jt < 8; ++jt) {
            __hip_bfloat16 hb = (__hip_bfloat16)(sc[jt][reg] * f1);
            Pls[rowoff + jt * 16 + l16] = *(unsigned short*)&hb;
        }
#pragma unroll
        for (int jt = 0; jt < 2; ++jt) {
            __hip_bfloat16 hb = (__hip_bfloat16)(sc2[jt][reg] * f2);
            Pls[rowoff + 128 + jt * 16 + l16] = *(unsigned short*)&hb;
        }
    }
    asm volatile("s_waitcnt lgkmcnt(0)" ::: "memory");  // wave-private P round-trip

    f32x4 o[4];
#pragma unroll
    for (int nt = 0; nt < 4; ++nt) o[nt] = (f32x4){0.f, 0.f, 0.f, 0.f};
#pragma unroll
    for (int kt = 0; kt < 5; ++kt) {
        short8 a = *(const short8*)&Pls[(w * 16 + l16) * PSTR + kt * 32 + quad * 8];
#pragma unroll
        for (int nt = 0; nt < 4; ++nt) {
            int dd = nt * 16 + l16;
            short8 b = *(const short8*)&Vts[dd * PSTR + kt * 32 + quad * 8];
            o[nt] = __builtin_amdgcn_mfma_f32_16x16x32_bf16(a, b, o[nt], 0, 0, 0);
        }
    }

#pragma unroll
    for (int nt = 0; nt < 4; ++nt) {
#pragma unroll
        for (int reg = 0; reg < 4; ++reg) {
            int row = t0 + rbase + reg;
            int col = h * 64 + nt * 16 + l16;
            Aout[(size_t)row * DM + col] = (__hip_bfloat16)(o[nt][reg]);
        }
    }
}

extern "C" void kernel_launch(void* const* d_in, const int* in_sizes, int n_in,
                              void* d_out, int out_size, void* d_ws, size_t ws_size,
                              hipStream_t stream)
{
    const float* x  = (const float*)d_in[0];
    const float* Wq = (const float*)d_in[1];
    const float* bq = (const float*)d_in[2];
    const float* Wk = (const float*)d_in[3];
    const float* bk = (const float*)d_in[4];
    const float* Wv = (const float*)d_in[5];
    const float* bv = (const float*)d_in[6];
    const float* Wo = (const float*)d_in[7];
    const float* bo = (const float*)d_in[8];
    const float* Wg = (const float*)d_in[9];
    const float* bg = (const float*)d_in[10];
    float* out = (float*)d_out;

    char* ws = (char*)d_ws;
    const size_t MB = 1024 * 1024;
    __hip_bfloat16* xb  = (__hip_bfloat16*)(ws + 0 * MB);   // 8 MB
    __hip_bfloat16* Qb  = (__hip_bfloat16*)(ws + 8 * MB);   // 8 MB
    __hip_bfloat16* Kb  = (__hip_bfloat16*)(ws + 16 * MB);  // 8 MB
    __hip_bfloat16* Vb  = (__hip_bfloat16*)(ws + 24 * MB);  // 8 MB
    __hip_bfloat16* Ab  = (__hip_bfloat16*)(ws + 32 * MB);  // 8 MB
    __hip_bfloat16* Wqb = (__hip_bfloat16*)(ws + 40 * MB);  // 2 MB
    __hip_bfloat16* Wkb = (__hip_bfloat16*)(ws + 42 * MB);  // 2 MB
    __hip_bfloat16* Wvb = (__hip_bfloat16*)(ws + 44 * MB);  // 2 MB
    __hip_bfloat16* Wob = (__hip_bfloat16*)(ws + 46 * MB);  // 2 MB
    __hip_bfloat16* CKb = (__hip_bfloat16*)(ws + 48 * MB);            // 256 KB
    __hip_bfloat16* CVb = (__hip_bfloat16*)(ws + 48 * MB + 256*1024); // 256 KB
    float* Gf           = (float*)(ws + 48 * MB + 512 * 1024);        // 256 KB
    __hip_bfloat16* Wgb = (__hip_bfloat16*)(ws + 48 * MB + 768*1024); // 32 KB

    cast_all<<<dim3(8208), 256, 0, stream>>>(x, Wq, Wk, Wv, Wo, Wg,
                                             xb, Wqb, Wkb, Wvb, Wob, Wgb);

    // Gate GEMM (only needs xb/Wgb; runs before the big QKV GEMM).
    g_mfma<<<dim3(64), 256, 0, stream>>>(xb, Wgb, bg, Gf);

    // Fused QKV GEMM + chunk-mean epilogue: grid (32, 24); group = blockIdx.y>>3.
    gemm128<__hip_bfloat16><<<dim3(32, 24), 256, 0, stream>>>(
        xb, Wqb, Wkb, Wvb, bq, bk, bv, Qb, Kb, Vb, CKb, CVb);

    attn_mfma<<<dim3(64, 16), 256, 0, stream>>>(Qb, Kb, Vb, CKb, CVb, Gf, Ab);

    // Output GEMM: 128x64 tiles (BK=32), grid (32, 16).
    gemm_n64<float><<<dim3(32, 16), 256, 0, stream>>>(Ab, Wob, bo, out);
}